// Round 12
// baseline (249.312 us; speedup 1.0000x reference)
//
#include <hip/hip_runtime.h>
#include <hip/hip_cooperative_groups.h>

namespace cg = cooperative_groups;

#define N_TOK 131072
#define TILE 64              // tokens per tile
#define NT_MAX 2064          // N_TOK/TILE + 16 tasks worth of padding tiles
#define NBLK 256             // 16 tasks x 16 blocks, XCD-mapped: 2 tasks per XCD

typedef __attribute__((ext_vector_type(8))) short s8v;
typedef __attribute__((ext_vector_type(4))) float f4v;
typedef unsigned short ushort_t;

__device__ __forceinline__ unsigned short f2bf(float x) {
    union { float f; unsigned u; } v; v.f = x;
    unsigned r = v.u + 0x7fffu + ((v.u >> 16) & 1u);   // RNE (prep only)
    return (unsigned short)(r >> 16);
}

// round-half-up pack of two f32 -> packed bf16x2 via v_perm_b32 (3 VALU ops)
__device__ __forceinline__ unsigned pk2(float a, float b) {
    union { float f; unsigned u; } x, y; x.f = a; y.f = b;
    return __byte_perm(x.u + 0x8000u, y.u + 0x8000u, 0x7632);
}

// tanh = 1 - 2/(e^2x+1); e^2x = exp2(x * 2*log2(e)): mul, exp2, add, rcp, fma
__device__ __forceinline__ float tanh_fast(float x) {
    float e = __builtin_amdgcn_exp2f(x * 2.8853900817779268f);
    float r = __builtin_amdgcn_rcpf(e + 1.0f);
    return __builtin_fmaf(-2.0f, r, 1.0f);
}

// ================================================================ fused kernel
// R0-R11: mlp plateaus at 63us across every structure (occupancy 18-72%, TILE
// 32/64/128, weight residency in L2/LDS/regs, 3-4 barriers, prefetch) -- but
// dur_us carries a ~98us NON-mlp residual: 2 extra kernel launches, full-device
// drains at each boundary, and sort using only 64/256 CUs. This round fuses
// prep+sort+mlp into ONE cooperative kernel (256 blocks x 512 thr, 1 block/CU):
//   Phase A: weight repack + per-chunk histogram (1 atomic/thread)
//   grid.sync()
//   Phase B: scan + scatter (each block owns 512 tokens, all CUs busy)
//   grid.sync()
//   Phase C: R11 mlp body (persistent per-task, XCD-mapped, 3-barrier, X dbuf)
// LDS 96KB (phase A/B overlay int scratch on H1/H2). Weights are L2-warm for C.
__launch_bounds__(512, 2)
__global__ void fused_kernel(const float* __restrict__ x_in,
                             const int* __restrict__ task,
                             const int* __restrict__ cmap,
                             const float* __restrict__ W0,
                             const float* __restrict__ b0,
                             const float* __restrict__ W1,
                             const float* __restrict__ b1,
                             const float* __restrict__ W2,
                             const float* __restrict__ b2,
                             ushort_t* W0p, ushort_t* W1p, ushort_t* W2p,
                             int* blockCounts, int* tbaseG, int* perm,
                             float* __restrict__ out) {
    __shared__ __align__(16) ushort_t Xb[2][8192];   // 16 KB each: 16 frags
    __shared__ __align__(16) ushort_t H1[16384];     // 32 frags = 32 KB
    __shared__ __align__(16) ushort_t H2[16384];     // 32 frags = 32 KB

    cg::grid_group grid = cg::this_grid();
    int p = blockIdx.x, t = threadIdx.x;
    int gid = p * 512 + t;                 // 0..131071, 1 token per thread

    // ======== Phase A: weight repack (gid<57344) + histogram ========
    if (gid < 57344) {
        int f = gid;
        const float* src; ushort_t* dst; int K, N;
        if (f < 16384)      { src = W0; dst = W0p; K = 128; N = 256; }
        else if (f < 49152) { src = W1; dst = W1p; K = 256; N = 256; f -= 16384; }
        else                { src = W2; dst = W2p; K = 256; N = 64;  f -= 49152; }
        int fpc = (N >> 4) * (K >> 5) * 64;       // fragments per copy
        int c = f / fpc, r = f % fpc;
        int lane = r & 63;
        int kt = (r >> 6) % (K >> 5);
        int ftile = (r >> 6) / (K >> 5);
        int n = ftile * 16 + (lane & 15);
        int kbase = kt * 32 + (lane >> 4) * 8;
        const float* s = src + (size_t)c * K * N + (size_t)kbase * N + n;
        s8v pk;
#pragma unroll
        for (int j = 0; j < 8; j++) pk[j] = (short)f2bf(s[(size_t)j * N]);
        *reinterpret_cast<s8v*>(dst + ((size_t)(c * fpc + r) << 3)) = pk;
    }
    int myTask = task[gid];
    {
        int* cnt = (int*)H1;               // 16 ints
        if (t < 16) cnt[t] = 0;
        __syncthreads();
        atomicAdd(&cnt[myTask], 1);
        __syncthreads();
        if (t < 16) blockCounts[p * 16 + t] = cnt[t];
    }
    grid.sync();

    // ======== Phase B: scan + scatter ========
    {
        int* cLds = (int*)H2;              // 256*16 = 4096 ints = 16 KB
        int* sc   = (int*)H1;              // tot[0..15] pref[16..31] rank[32..47]
                                           // tokBase[48..63] tbase[64..80]
        for (int i = t; i < 4096; i += 512) cLds[i] = blockCounts[i];
        if (t < 16) sc[32 + t] = 0;
        __syncthreads();
        if (t < 16) {
            int tot = 0, pf = 0;
            for (int bb = 0; bb < 256; bb++) {
                int v = cLds[bb * 16 + t];
                tot += v;
                if (bb < p) pf += v;
            }
            sc[t] = tot; sc[16 + t] = pf;
        }
        __syncthreads();
        if (t == 0) {
            int tok = 0, tile = 0;
            for (int k2 = 0; k2 < 16; k2++) {
                sc[48 + k2] = tok;
                sc[64 + k2] = tile;
                int ntk = (sc[k2] + TILE - 1) >> 6;
                tok += ntk * TILE;
                tile += ntk;
            }
            sc[80] = tile;
        }
        __syncthreads();
        if (p == 0) {
            if (t < 17) tbaseG[t] = sc[64 + t];
            // fill padding slots with -1
            for (int i = t; i < 16 * TILE; i += 512) {
                int k2 = i >> 6, off = i & (TILE - 1);
                int idx = sc[k2] + off;
                int lim = ((sc[k2] + TILE - 1) >> 6) << 6;
                if (idx < lim) perm[sc[48 + k2] + idx] = -1;
            }
        }
        int my = atomicAdd(&sc[32 + myTask], 1);
        perm[sc[48 + myTask] + sc[16 + myTask] + my] = gid;
    }
    grid.sync();

    // ======== Phase C: persistent MLP (R11 body) ========
    int x = p & 7, s = p >> 3;            // xcd (HW: blockIdx%8), slot-on-xcd
    int k = 2 * x + (s >> 4), sub = s & 15;
    int tBeg = tbaseG[k], tEnd = tbaseG[k + 1];
    if (tBeg + sub >= tEnd) return;       // block-uniform; no grid syncs remain

    int c0 = cmap[k], c1 = cmap[16 + k], c2 = cmap[32 + k];

    int w = t >> 6;                 // wave 0..7
    int lane = t & 63;
    int l15 = lane & 15, lq = lane >> 4;
    int mt2 = w & 3, ntb2 = (w >> 2) * 2;   // layer-2 tile assignment

    const ushort_t* Wc0 = W0p + (size_t)c0 * 32768;
    const ushort_t* Wc1 = W1p + (size_t)c1 * 65536;
    const ushort_t* Wc2 = W2p + (size_t)c2 * 16384;

    // biases, resident
    f4v bv0[2], bv1[2], bv2;
#pragma unroll
    for (int mi = 0; mi < 2; mi++) {
        bv0[mi] = *reinterpret_cast<const f4v*>(b0 + c0 * 256 + (2 * w + mi) * 16 + lq * 4);
        bv1[mi] = *reinterpret_cast<const f4v*>(b1 + c1 * 256 + (2 * w + mi) * 16 + lq * 4);
    }
    bv2 = *reinterpret_cast<const f4v*>(b2 + c2 * 64 + mt2 * 16 + lq * 4);

    // staging coords: thread owns token r2, k-range q*16..q*16+15
    int r2 = t >> 3, q = t & 7;
    int fragid = (r2 >> 4) * 4 + (q >> 1);
    int lp0 = (r2 & 15) + 16 * ((q & 1) * 2);
    const float4* xbase = reinterpret_cast<const float4*>(x_in);

    // ---- prologue: gather tile0, write Xb[0], publish
    int tile = tBeg + sub;
    {
        int ptok = perm[tile * TILE + r2];
        float4 v0 = make_float4(0.f, 0.f, 0.f, 0.f), v1 = v0, v2 = v0, v3 = v0;
        if ((unsigned)ptok < (unsigned)N_TOK) {
            const float4* src = xbase + (size_t)ptok * 32 + q * 4;
            v0 = src[0]; v1 = src[1]; v2 = src[2]; v3 = src[3];
        }
        uint4 pk0, pk1;
        pk0.x = pk2(v0.x, v0.y); pk0.y = pk2(v0.z, v0.w);
        pk0.z = pk2(v1.x, v1.y); pk0.w = pk2(v1.z, v1.w);
        pk1.x = pk2(v2.x, v2.y); pk1.y = pk2(v2.z, v2.w);
        pk1.z = pk2(v3.x, v3.y); pk1.w = pk2(v3.z, v3.w);
        *reinterpret_cast<uint4*>(&Xb[0][(fragid * 64 + lp0) << 3]) = pk0;
        *reinterpret_cast<uint4*>(&Xb[0][(fragid * 64 + lp0 + 16) << 3]) = pk1;
    }
    __syncthreads();

    int cur = 0;
    for (; tile < tEnd; tile += 16) {
        int ntile = tile + 16;
        bool hasNext = ntile < tEnd;

        // ---- issue next tile's gather at L0-top: drain hides under L0+L1
        float4 a0 = make_float4(0.f, 0.f, 0.f, 0.f), a1 = a0, a2 = a0, a3 = a0;
        if (hasNext) {
            int ptok = perm[ntile * TILE + r2];
            if ((unsigned)ptok < (unsigned)N_TOK) {
                const float4* src = xbase + (size_t)ptok * 32 + q * 4;
                a0 = src[0]; a1 = src[1]; a2 = src[2]; a3 = src[3];
            }
        }

        // ---- Layer 0: H1^T = W0^T X^T. Wave w: ftiles {2w,2w+1} x 4 token tiles.
        {
            f4v acc[2][4];
#pragma unroll
            for (int mi = 0; mi < 2; mi++)
#pragma unroll
                for (int nt = 0; nt < 4; nt++)
                    acc[mi][nt] = bv0[mi];
#pragma unroll
            for (int kt = 0; kt < 4; kt++) {
                s8v wa[2], xb[4];
#pragma unroll
                for (int mi = 0; mi < 2; mi++)
                    wa[mi] = *reinterpret_cast<const s8v*>(Wc0 + ((((2 * w + mi) * 4 + kt) * 64 + lane) << 3));
#pragma unroll
                for (int nt = 0; nt < 4; nt++)
                    xb[nt] = *reinterpret_cast<const s8v*>(&Xb[cur][((nt * 4 + kt) * 64 + lane) << 3]);
#pragma unroll
                for (int mi = 0; mi < 2; mi++)
#pragma unroll
                    for (int nt = 0; nt < 4; nt++)
                        acc[mi][nt] = __builtin_amdgcn_mfma_f32_16x16x32_bf16(wa[mi], xb[nt], acc[mi][nt], 0, 0, 0);
            }
#pragma unroll
            for (int mi = 0; mi < 2; mi++) {
                int ft = 2 * w + mi;
                int kt_h = ft >> 1;
                int lanep = l15 + 16 * ((ft & 1) * 2 + (lq >> 1));
                int j0 = (lq & 1) * 4;
#pragma unroll
                for (int nt = 0; nt < 4; nt++) {
                    float t0 = tanh_fast(acc[mi][nt][0]);
                    float t1 = tanh_fast(acc[mi][nt][1]);
                    float t2 = tanh_fast(acc[mi][nt][2]);
                    float t3 = tanh_fast(acc[mi][nt][3]);
                    uint2 pk; pk.x = pk2(t0, t1); pk.y = pk2(t2, t3);
                    *reinterpret_cast<uint2*>(&H1[(((nt * 8 + kt_h) * 64 + lanep) << 3) + j0]) = pk;
                }
            }
        }
        __syncthreads();   // B2: publish H1

        // ---- Layer 1: H2^T = W1^T H1^T; mid-phase, stage X[tile+16] into Xb[cur^1]
        {
            f4v acc[2][4];
#pragma unroll
            for (int mi = 0; mi < 2; mi++)
#pragma unroll
                for (int nt = 0; nt < 4; nt++)
                    acc[mi][nt] = bv1[mi];
#pragma unroll
            for (int kt = 0; kt < 8; kt++) {
                s8v wa[2], xb[4];
#pragma unroll
                for (int mi = 0; mi < 2; mi++)
                    wa[mi] = *reinterpret_cast<const s8v*>(Wc1 + ((((2 * w + mi) * 8 + kt) * 64 + lane) << 3));
#pragma unroll
                for (int nt = 0; nt < 4; nt++)
                    xb[nt] = *reinterpret_cast<const s8v*>(&H1[((nt * 8 + kt) * 64 + lane) << 3]);
#pragma unroll
                for (int mi = 0; mi < 2; mi++)
#pragma unroll
                    for (int nt = 0; nt < 4; nt++)
                        acc[mi][nt] = __builtin_amdgcn_mfma_f32_16x16x32_bf16(wa[mi], xb[nt], acc[mi][nt], 0, 0, 0);
            }
            // stage next X (gather issued at L0-top; wait hides under the MFMAs above)
            if (hasNext) {
                uint4 pk0, pk1;
                pk0.x = pk2(a0.x, a0.y); pk0.y = pk2(a0.z, a0.w);
                pk0.z = pk2(a1.x, a1.y); pk0.w = pk2(a1.z, a1.w);
                pk1.x = pk2(a2.x, a2.y); pk1.y = pk2(a2.z, a2.w);
                pk1.z = pk2(a3.x, a3.y); pk1.w = pk2(a3.z, a3.w);
                *reinterpret_cast<uint4*>(&Xb[cur ^ 1][(fragid * 64 + lp0) << 3]) = pk0;
                *reinterpret_cast<uint4*>(&Xb[cur ^ 1][(fragid * 64 + lp0 + 16) << 3]) = pk1;
            }
#pragma unroll
            for (int mi = 0; mi < 2; mi++) {
                int ft = 2 * w + mi;
                int kt_h = ft >> 1;
                int lanep = l15 + 16 * ((ft & 1) * 2 + (lq >> 1));
                int j0 = (lq & 1) * 4;
#pragma unroll
                for (int nt = 0; nt < 4; nt++) {
                    float t0 = tanh_fast(acc[mi][nt][0]);
                    float t1 = tanh_fast(acc[mi][nt][1]);
                    float t2 = tanh_fast(acc[mi][nt][2]);
                    float t3 = tanh_fast(acc[mi][nt][3]);
                    uint2 pk; pk.x = pk2(t0, t1); pk.y = pk2(t2, t3);
                    *reinterpret_cast<uint2*>(&H2[(((nt * 8 + kt_h) * 64 + lanep) << 3) + j0]) = pk;
                }
            }
        }
        __syncthreads();   // B3: publish H2 (and X[tile+16])

        // ---- Layer 2: O^T = W2^T H2^T. 4 mt x 4 nt tiles / 8 waves = 2 tiles/wave.
        {
            int tok0 = perm[tile * TILE + ntb2 * 16 + l15];
            int tok1 = perm[tile * TILE + (ntb2 + 1) * 16 + l15];
            f4v acc[2];
            acc[0] = bv2; acc[1] = bv2;
#pragma unroll
            for (int kt = 0; kt < 8; kt++) {
                s8v wa = *reinterpret_cast<const s8v*>(Wc2 + (((mt2 * 8 + kt) * 64 + lane) << 3));
#pragma unroll
                for (int e = 0; e < 2; e++) {
                    s8v xb = *reinterpret_cast<const s8v*>(&H2[(((ntb2 + e) * 8 + kt) * 64 + lane) << 3]);
                    acc[e] = __builtin_amdgcn_mfma_f32_16x16x32_bf16(wa, xb, acc[e], 0, 0, 0);
                }
            }
#pragma unroll
            for (int e = 0; e < 2; e++) {
                int tok = e ? tok1 : tok0;
                if ((unsigned)tok < (unsigned)N_TOK) {
                    float4 o;
                    o.x = acc[e][0]; o.y = acc[e][1]; o.z = acc[e][2]; o.w = acc[e][3];
                    *reinterpret_cast<float4*>(out + (size_t)tok * 64 + mt2 * 16 + lq * 4) = o;
                }
            }
        }
        __syncthreads();   // B4: H2 reads done -> L1[i+1] may overwrite
        cur ^= 1;
    }
}

// ---------------------------------------------------------------- launch
extern "C" void kernel_launch(void* const* d_in, const int* in_sizes, int n_in,
                              void* d_out, int out_size, void* d_ws, size_t ws_size,
                              hipStream_t stream) {
    const float* inputs = (const float*)d_in[0];
    const int*   task   = (const int*)d_in[1];
    const int*   cmap   = (const int*)d_in[2];
    const float* W0     = (const float*)d_in[3];
    const float* b0     = (const float*)d_in[4];
    const float* W1     = (const float*)d_in[5];
    const float* b1     = (const float*)d_in[6];
    const float* W2     = (const float*)d_in[7];
    const float* b2     = (const float*)d_in[8];
    float* out = (float*)d_out;

    char* ws = (char*)d_ws;
    int* blockCounts = (int*)(ws + 0);            // 256*16*4 = 16384 B
    int* tbaseG      = (int*)(ws + 16384);        // 17*4 = 68 B, padded to 128
    int* perm        = (int*)(ws + 16512);        // 2064*64*4 = 528384 B -> ends 544896
    ushort_t* W0p    = (ushort_t*)(ws + 544896);  // 262144 B -> 807040
    ushort_t* W1p    = (ushort_t*)(ws + 807040);  // 524288 B -> 1331328
    ushort_t* W2p    = (ushort_t*)(ws + 1331328); // 131072 B -> total ~1.46 MB

    void* args[] = {
        (void*)&inputs, (void*)&task, (void*)&cmap,
        (void*)&W0, (void*)&b0, (void*)&W1, (void*)&b1, (void*)&W2, (void*)&b2,
        (void*)&W0p, (void*)&W1p, (void*)&W2p,
        (void*)&blockCounts, (void*)&tbaseG, (void*)&perm,
        (void*)&out
    };
    hipLaunchCooperativeKernel((const void*)fused_kernel, dim3(NBLK), dim3(512),
                               args, 0, stream);
}